// Round 14
// baseline (44.106 us; speedup 1.0000x reference)
//
#include <hip/hip_runtime.h>
#include <hip/hip_bf16.h>

typedef __bf16 bf16x8 __attribute__((ext_vector_type(8)));
typedef __bf16 bf16x4 __attribute__((ext_vector_type(4)));
typedef float  f32x4  __attribute__((ext_vector_type(4)));
typedef unsigned short u16;

#define NPROT 8192
#define NLIG  2048
#define DMODEL 128
#define NHEAD 8
#define NBATCH 32
#define PPB 256
#define LPB 64

__device__ __forceinline__ u16 f2bf(float f){
  union { float f; unsigned int u; } v; v.f = f;
  return (u16)((v.u + 0x7FFFu + ((v.u >> 16) & 1u)) >> 16);
}

__device__ __forceinline__ bf16x8 cvt8(const float* p){
  float4 a = *(const float4*)p, b = *(const float4*)(p + 4);
  bf16x8 r;
  r[0]=(__bf16)a.x; r[1]=(__bf16)a.y; r[2]=(__bf16)a.z; r[3]=(__bf16)a.w;
  r[4]=(__bf16)b.x; r[5]=(__bf16)b.y; r[6]=(__bf16)b.z; r[7]=(__bf16)b.w;
  return r;
}

// ================= K1: qkv GEMM (LDS-staged A/W/C) + fragment-linear weight prep =================
struct QkvJob { const float* A; const float* Wsrc[3]; u16* outB; int N; int blockStart; };
struct TJob { const float* src; u16* dst; int M, K, tilesX, blockStart; };
struct L1Args {
  QkvJob qjobs[2];
  int nQkv;
  int nprep;
  TJob pjobs[10];
};

__global__ __launch_bounds__(256) void l1_kernel(L1Args a){
  __shared__ u16 Wl[64][136];
  __shared__ u16 Al[64][136];
  __shared__ float tile[32][33];
  // XCD-bijective swizzle: grid = 1312 = 8 * 164
  int bid = (int)blockIdx.x;
  bid = (bid & 7) * 164 + (bid >> 3);
  int tid = (int)threadIdx.x;
  if (bid < a.nQkv){
    int j = (bid >= a.qjobs[1].blockStart) ? 1 : 0;
    const QkvJob jb = a.qjobs[j];
    int t = bid - jb.blockStart;
    int tn = t / 6, tm = t - tn * 6;
    {
      int midx = tm >> 1;
      int cb64 = (tm & 1) * 64;
      const float* Ws = jb.Wsrc[midx];
      int kr = tid >> 2;
      int cb = (tid & 3) * 16;
      #pragma unroll
      for (int p = 0; p < 2; ++p){
        int k = p * 64 + kr;
        const float* srcp = Ws + (size_t)k * 128 + cb64 + cb;
        float4 v0 = *(const float4*)srcp,     v1 = *(const float4*)(srcp + 4);
        float4 v2 = *(const float4*)(srcp+8), v3 = *(const float4*)(srcp + 12);
        float tmp[16] = {v0.x,v0.y,v0.z,v0.w, v1.x,v1.y,v1.z,v1.w,
                         v2.x,v2.y,v2.z,v2.w, v3.x,v3.y,v3.z,v3.w};
        #pragma unroll
        for (int i = 0; i < 16; ++i) Wl[cb + i][k] = f2bf(tmp[i]);
      }
    }
    {
      const float* Asrc = jb.A + (size_t)(tn * 64) * 128;
      #pragma unroll
      for (int p = 0; p < 8; ++p){
        int idx = p * 256 + tid;
        int r = idx >> 5, c4 = (idx & 31) * 4;
        float4 v = *(const float4*)(Asrc + (size_t)r * 128 + c4);
        Al[r][c4+0] = f2bf(v.x); Al[r][c4+1] = f2bf(v.y);
        Al[r][c4+2] = f2bf(v.z); Al[r][c4+3] = f2bf(v.w);
      }
    }
    __syncthreads();
    int w = tid >> 6, l = tid & 63;
    int rloc = (w >> 1) * 32;
    int cloc = (w & 1) * 32;
    int lr = l & 15, lk = (l >> 4) * 8;
    f32x4 a00 = {0.f,0.f,0.f,0.f}, a01 = a00, a10 = a00, a11 = a00;
    #pragma unroll
    for (int kk = 0; kk < 128; kk += 32){
      bf16x8 a0 = *(const bf16x8*)&Al[rloc + lr][kk + lk];
      bf16x8 a1 = *(const bf16x8*)&Al[rloc + 16 + lr][kk + lk];
      bf16x8 b0 = *(const bf16x8*)&Wl[cloc + lr][kk + lk];
      bf16x8 b1 = *(const bf16x8*)&Wl[cloc + 16 + lr][kk + lk];
      a00 = __builtin_amdgcn_mfma_f32_16x16x32_bf16(a0, b0, a00, 0, 0, 0);
      a01 = __builtin_amdgcn_mfma_f32_16x16x32_bf16(a0, b1, a01, 0, 0, 0);
      a10 = __builtin_amdgcn_mfma_f32_16x16x32_bf16(a1, b0, a10, 0, 0, 0);
      a11 = __builtin_amdgcn_mfma_f32_16x16x32_bf16(a1, b1, a11, 0, 0, 0);
    }
    __syncthreads();
    {
      f32x4 av[2][2] = {{a00, a01}, {a10, a11}};
      int lg4 = l >> 4;
      #pragma unroll
      for (int i = 0; i < 2; ++i)
        #pragma unroll
        for (int jj = 0; jj < 2; ++jj)
          #pragma unroll
          for (int e = 0; e < 4; ++e)
            Al[rloc + i * 16 + lg4 * 4 + e][cloc + jj * 16 + lr] = f2bf(av[i][jj][e]);
    }
    __syncthreads();
    {
      int row = tid >> 2;
      int hseg = tid & 3;
      int m = tm >> 1;
      int h = (tm & 1) * 4 + hseg;
      const u16* srcl = &Al[row][hseg * 16];
      u16* dst = jb.outB + ((size_t)m * NHEAD + h) * (size_t)jb.N * 16
                         + (size_t)(tn * 64 + row) * 16;
      *(bf16x8*)dst = *(const bf16x8*)srcl;
      *(bf16x8*)(dst + 8) = *(const bf16x8*)(srcl + 8);
    }
  } else {
    int pb = bid - a.nQkv;
    int j = 0;
    while (j + 1 < a.nprep && pb >= a.pjobs[j + 1].blockStart) ++j;
    const TJob jb = a.pjobs[j];
    int t = pb - jb.blockStart;
    int tm = t % jb.tilesX, tk = t / jb.tilesX;
    int c = tid & 31, r0 = tid >> 5;
    #pragma unroll
    for (int p = 0; p < 4; ++p)
      tile[r0 + p * 8][c] = jb.src[(size_t)(tk * 32 + r0 + p * 8) * jb.M + tm * 32 + c];
    __syncthreads();
    {
      int c2 = tid >> 7;
      int lch = (tid >> 1) & 63;
      int eh = (tid & 1) * 4;
      int kl = (lch >> 4) * 8 + eh;
      int ml = c2 * 16 + (lch & 15);
      ushort4 o;
      o.x = f2bf(tile[kl + 0][ml]);
      o.y = f2bf(tile[kl + 1][ml]);
      o.z = f2bf(tile[kl + 2][ml]);
      o.w = f2bf(tile[kl + 3][ml]);
      size_t off = ((size_t)(tm * 2 + c2) * (jb.K >> 5) + tk) * 512 + lch * 8 + eh;
      *(ushort4*)&jb.dst[off] = o;
    }
  }
}

// ================= K2: fused attn + tail; weights loaded at point-of-use (R12 style) =================
struct K2Args {
  const u16 *qkv_p, *qkv_l;
  const float *h_f[2];
  const u16 *WgT[2], *WgB[2], *WuT[2];
  const float *bg[2], *bu[2], *lng[2], *lnb[2];
  const u16 *W1T[2], *W2T[2];
  const float *b1[2], *b2[2];
  float* out[2];
};

struct K2B {
  float hu[32 * 132];
  union { float hstg[32 * 132]; u16 t[32 * 520]; } x;
};

__global__ __launch_bounds__(512) void k2_kernel(K2Args args){
  __shared__ __align__(16) union {
    struct { u16 vT[8 * 1152]; u16 P[8 * 2304]; } a;
    K2B b;
  } su;
  __shared__ __align__(16) u16 s_ctx[32 * 128];

  int bid = (int)blockIdx.x;
  int tid = (int)threadIdx.x;
  int w = tid >> 6, l = tid & 63, lr = l & 15, lg4 = l >> 4;
  int lk = lg4 * 8;

  int side, rowbase, batch, NC;
  if (bid < NLIG / 32){ side = 1; rowbase = bid * 32; batch = rowbase >> 6; NC = 4; }
  else { side = 0; rowbase = (bid - NLIG / 32) * 32; batch = rowbase >> 8; NC = 1; }

  int NRs = side == 0 ? NPROT : NLIG;
  int NRo = side == 0 ? NLIG : NPROT;
  int orowoff = side == 0 ? batch * LPB : batch * PPB;
  const u16* qbase = (side == 0 ? args.qkv_p : args.qkv_l);
  const u16* obase = (side == 0 ? args.qkv_l : args.qkv_p);
  const u16* kbase = obase + (size_t)NHEAD * NRo * 16;
  const u16* vbase = obase + (size_t)2 * NHEAD * NRo * 16;

  bf16x8 zero8;
  #pragma unroll
  for (int i = 0; i < 8; ++i) zero8[i] = (__bf16)0.f;

  u16* vTw = su.a.vT + w * 1152;
  u16* Pw  = su.a.P  + w * 2304;
  int h = w;

  // ---- entry prefetch: h residual (issue early, commit after attention) ----
  float4 hreg0, hreg1;
  {
    const float* hsrc = args.h_f[side] + (size_t)rowbase * 128;
    int i1 = 512 + tid;
    hreg0 = *(const float4*)(hsrc + (size_t)(tid >> 5) * 128 + (tid & 31) * 4);
    hreg1 = *(const float4*)(hsrc + (size_t)(i1 >> 5) * 128 + (i1 & 31) * 4);
  }

  // ---- attention: online softmax over 64-key chunks, V/K next-chunk pipeline ----
  {
    bf16x8 qf[2];
    #pragma unroll
    for (int qt = 0; qt < 2; ++qt)
      qf[qt] = (l < 32)
        ? *(const bf16x8*)(qbase + ((size_t)h * NRs + rowbase + qt * 16 + lr) * 16 + lk)
        : zero8;
    bf16x8 vr0, vr1, kn[4];
    {
      const u16* vs = vbase + ((size_t)h * NRo + orowoff + l) * 16;
      vr0 = *(const bf16x8*)vs;
      vr1 = *(const bf16x8*)(vs + 8);
      #pragma unroll
      for (int kt = 0; kt < 4; ++kt)
        kn[kt] = (l < 32)
          ? *(const bf16x8*)(kbase + ((size_t)h * NRo + orowoff + kt * 16 + lr) * 16 + lk)
          : zero8;
    }
    f32x4 Ot[2]; float mv[2], ls[2];
    #pragma unroll
    for (int qt = 0; qt < 2; ++qt){ Ot[qt] = (f32x4){0.f,0.f,0.f,0.f}; mv[qt] = -1e30f; ls[qt] = 0.f; }
    for (int c = 0; c < NC; ++c){
      #pragma unroll
      for (int i = 0; i < 8; ++i){
        vTw[i * 72 + l]       = ((const u16*)&vr0)[i];
        vTw[(i + 8) * 72 + l] = ((const u16*)&vr1)[i];
      }
      bf16x8 kf[4];
      #pragma unroll
      for (int kt = 0; kt < 4; ++kt) kf[kt] = kn[kt];
      if (c + 1 < NC){
        const u16* vs = vbase + ((size_t)h * NRo + orowoff + (c + 1) * 64 + l) * 16;
        vr0 = *(const bf16x8*)vs;
        vr1 = *(const bf16x8*)(vs + 8);
        #pragma unroll
        for (int kt = 0; kt < 4; ++kt)
          kn[kt] = (l < 32)
            ? *(const bf16x8*)(kbase + ((size_t)h * NRo + orowoff + (c + 1) * 64 + kt * 16 + lr) * 16 + lk)
            : zero8;
      }
      f32x4 sa[4][2];
      #pragma unroll
      for (int kt = 0; kt < 4; ++kt)
        #pragma unroll
        for (int qt = 0; qt < 2; ++qt)
          sa[kt][qt] = __builtin_amdgcn_mfma_f32_16x16x32_bf16(kf[kt], qf[qt], (f32x4){0.f,0.f,0.f,0.f}, 0, 0, 0);
      #pragma unroll
      for (int qt = 0; qt < 2; ++qt){
        float cm = -1e30f;
        #pragma unroll
        for (int kt = 0; kt < 4; ++kt)
          #pragma unroll
          for (int e = 0; e < 4; ++e) cm = fmaxf(cm, sa[kt][qt][e]);
        cm = fmaxf(cm, __shfl_xor(cm, 16)); cm = fmaxf(cm, __shfl_xor(cm, 32));
        float mn, resc;
        if (c == 0){ mn = cm; resc = 0.f; }
        else { mn = fmaxf(mv[qt], cm); resc = __expf((mv[qt] - mn) * 0.25f); }
        mv[qt] = mn;
        float cs = 0.f;
        #pragma unroll
        for (int kt = 0; kt < 4; ++kt){
          bf16x4 pk;
          #pragma unroll
          for (int e = 0; e < 4; ++e){
            float p = __expf((sa[kt][qt][e] - mn) * 0.25f);
            cs += p; pk[e] = (__bf16)p;
          }
          *(bf16x4*)&Pw[(size_t)(qt * 16 + lr) * 72 + kt * 16 + lg4 * 4] = pk;
        }
        cs += __shfl_xor(cs, 16); cs += __shfl_xor(cs, 32);
        ls[qt] = ls[qt] * resc + cs;
        Ot[qt] = Ot[qt] * resc;
      }
      #pragma unroll
      for (int ks = 0; ks < 2; ++ks){
        bf16x8 va = *(const bf16x8*)&vTw[(size_t)lr * 72 + ks * 32 + lg4 * 8];
        #pragma unroll
        for (int qt = 0; qt < 2; ++qt){
          bf16x8 pb = *(const bf16x8*)&Pw[(size_t)(qt * 16 + lr) * 72 + ks * 32 + lg4 * 8];
          Ot[qt] = __builtin_amdgcn_mfma_f32_16x16x32_bf16(va, pb, Ot[qt], 0, 0, 0);
        }
      }
    }
    #pragma unroll
    for (int qt = 0; qt < 2; ++qt){
      float inv = 1.f / ls[qt];
      int q = qt * 16 + lr;
      int dbase = h * 16 + lg4 * 4;
      bf16x4 ov;
      #pragma unroll
      for (int e = 0; e < 4; ++e) ov[e] = (__bf16)(Ot[qt][e] * inv);
      *(bf16x4*)&s_ctx[(size_t)q * 128 + (dbase ^ ((q & 7) << 3))] = ov;
    }
  }
  __syncthreads();

  // ---- commit prefetched h to LDS ----
  {
    int i1 = 512 + tid;
    *(float4*)&su.b.x.hstg[(size_t)(tid >> 5) * 132 + (tid & 31) * 4] = hreg0;
    *(float4*)&su.b.x.hstg[(size_t)(i1 >> 5) * 132 + (i1 & 31) * 4] = hreg1;
  }
  __syncthreads();

  // ---- stage 1: glin (K=256: h|ctx) + u (K=128: ctx); frag-linear weight streams ----
  {
    bf16x8 wg[4], wc[4], wu[4];
    {
      const u16* bgp = args.WgT[side] + (size_t)(w * 4) * 512 + l * 8;
      const u16* bcp = args.WgB[side] + (size_t)(w * 4) * 512 + l * 8;
      const u16* bup = args.WuT[side] + (size_t)(w * 4) * 512 + l * 8;
      #pragma unroll
      for (int kb = 0; kb < 4; ++kb) wg[kb] = *(const bf16x8*)(bgp + kb * 512);
      #pragma unroll
      for (int kb = 0; kb < 4; ++kb) wc[kb] = *(const bf16x8*)(bcp + kb * 512);
      #pragma unroll
      for (int kb = 0; kb < 4; ++kb) wu[kb] = *(const bf16x8*)(bup + kb * 512);
    }
    f32x4 g0 = {0.f,0.f,0.f,0.f}, g1 = g0, u0 = g0, u1 = g0;
    const float* hst = su.b.x.hstg;
    int swa = (lr & 7) << 3;
    #pragma unroll
    for (int kb = 0; kb < 4; ++kb){
      int kk = kb * 32;
      bf16x8 ah0 = cvt8(hst + (size_t)lr * 132 + kk);
      bf16x8 ah1 = cvt8(hst + (size_t)(16 + lr) * 132 + kk);
      bf16x8 ac0 = *(const bf16x8*)&s_ctx[(size_t)lr * 128 + ((kk + lk) ^ swa)];
      bf16x8 ac1 = *(const bf16x8*)&s_ctx[(size_t)(16 + lr) * 128 + ((kk + lk) ^ swa)];
      g0 = __builtin_amdgcn_mfma_f32_16x16x32_bf16(ah0, wg[kb], g0, 0, 0, 0);
      g1 = __builtin_amdgcn_mfma_f32_16x16x32_bf16(ah1, wg[kb], g1, 0, 0, 0);
      g0 = __builtin_amdgcn_mfma_f32_16x16x32_bf16(ac0, wc[kb], g0, 0, 0, 0);
      g1 = __builtin_amdgcn_mfma_f32_16x16x32_bf16(ac1, wc[kb], g1, 0, 0, 0);
      u0 = __builtin_amdgcn_mfma_f32_16x16x32_bf16(ac0, wu[kb], u0, 0, 0, 0);
      u1 = __builtin_amdgcn_mfma_f32_16x16x32_bf16(ac1, wu[kb], u1, 0, 0, 0);
    }
    int col = w * 16 + lr;
    float bgc = args.bg[side][col];
    float buc = args.bu[side][col];
    #pragma unroll
    for (int i = 0; i < 2; ++i){
      f32x4 gv4 = i ? g1 : g0;
      f32x4 uv4 = i ? u1 : u0;
      #pragma unroll
      for (int e = 0; e < 4; ++e){
        int row = i * 16 + lg4 * 4 + e;
        float gv = gv4[e] + bgc;
        float uv = uv4[e] + buc;
        float hv = hst[(size_t)row * 132 + col];
        float sg = 1.f / (1.f + __expf(-gv));
        su.b.hu[(size_t)row * 132 + col] = hv + sg * uv;
      }
    }
  }
  __syncthreads();

  // ---- stage 2: LayerNorm -> xln (overwrites s_ctx, swizzled); 16 thr/row ----
  {
    int r = tid >> 4;
    int sub = tid & 15;
    float x[8];
    #pragma unroll
    for (int i = 0; i < 2; ++i){
      float4 v4 = *(const float4*)&su.b.hu[(size_t)r * 132 + sub * 8 + i * 4];
      x[i*4+0] = v4.x; x[i*4+1] = v4.y; x[i*4+2] = v4.z; x[i*4+3] = v4.w;
    }
    float s = 0.f;
    #pragma unroll
    for (int i = 0; i < 8; ++i) s += x[i];
    s += __shfl_xor(s, 1); s += __shfl_xor(s, 2); s += __shfl_xor(s, 4); s += __shfl_xor(s, 8);
    float mu = s * (1.f / 128.f);
    float vv = 0.f;
    #pragma unroll
    for (int i = 0; i < 8; ++i){ float d = x[i] - mu; vv += d * d; }
    vv += __shfl_xor(vv, 1); vv += __shfl_xor(vv, 2); vv += __shfl_xor(vv, 4); vv += __shfl_xor(vv, 8);
    float rs = rsqrtf(vv * (1.f / 128.f) + 1e-5f);
    const float* lg2 = args.lng[side];
    const float* lb = args.lnb[side];
    int sw = (r & 7) << 3;
    #pragma unroll
    for (int i = 0; i < 8; ++i){
      int col = sub * 8 + i;
      s_ctx[(size_t)r * 128 + (col ^ sw)] = f2bf((x[i] - mu) * rs * lg2[col] + lb[col]);
    }
  }
  __syncthreads();

  // ---- stage 3: FFN1 t = relu(xln @ W1 + b1); frag-linear W1 stream ----
  {
    bf16x8 w1f[16];
    {
      const u16* b1p = args.W1T[side] + (size_t)(w * 16) * 512 + l * 8;
      #pragma unroll
      for (int q = 0; q < 16; ++q) w1f[q] = *(const bf16x8*)(b1p + q * 512);
    }
    f32x4 acc[2][4];
    #pragma unroll
    for (int i = 0; i < 2; ++i)
      #pragma unroll
      for (int jj = 0; jj < 4; ++jj) acc[i][jj] = (f32x4){0.f,0.f,0.f,0.f};
    int sw0 = (lr & 7) << 3;
    #pragma unroll
    for (int kb = 0; kb < 4; ++kb){
      int kk = kb * 32;
      bf16x8 a0 = *(const bf16x8*)&s_ctx[(size_t)lr * 128 + ((kk + lk) ^ sw0)];
      bf16x8 a1 = *(const bf16x8*)&s_ctx[(size_t)(16 + lr) * 128 + ((kk + lk) ^ sw0)];
      #pragma unroll
      for (int jj = 0; jj < 4; ++jj){
        acc[0][jj] = __builtin_amdgcn_mfma_f32_16x16x32_bf16(a0, w1f[jj * 4 + kb], acc[0][jj], 0, 0, 0);
        acc[1][jj] = __builtin_amdgcn_mfma_f32_16x16x32_bf16(a1, w1f[jj * 4 + kb], acc[1][jj], 0, 0, 0);
      }
    }
    const float* b1v = args.b1[side];
    u16* t_flat = su.b.x.t;
    #pragma unroll
    for (int i = 0; i < 2; ++i)
      #pragma unroll
      for (int jj = 0; jj < 4; ++jj)
        #pragma unroll
        for (int e = 0; e < 4; ++e){
          int row = i * 16 + lg4 * 4 + e;
          int col = w * 64 + jj * 16 + lr;
          float v = fmaxf(acc[i][jj][e] + b1v[col], 0.f);
          t_flat[(size_t)row * 520 + (col ^ ((row & 7) << 3))] = f2bf(v);
        }
  }
  __syncthreads();

  // ---- stage 4: FFN2 out = t @ W2 + b2 + hu; frag-linear W2 stream, dual-parity acc ----
  {
    bf16x8 w2f[16];
    {
      const u16* b2p = args.W2T[side] + (size_t)(w * 16) * 512 + l * 8;
      #pragma unroll
      for (int q = 0; q < 16; ++q) w2f[q] = *(const bf16x8*)(b2p + q * 512);
    }
    f32x4 o[2][2];
    #pragma unroll
    for (int i = 0; i < 2; ++i)
      #pragma unroll
      for (int p = 0; p < 2; ++p) o[i][p] = (f32x4){0.f,0.f,0.f,0.f};
    const u16* t_flat = su.b.x.t;
    int sw0 = (lr & 7) << 3;
    #pragma unroll
    for (int kb = 0; kb < 16; kb += 2){
      int kk = kb * 32;
      bf16x8 a0e = *(const bf16x8*)&t_flat[(size_t)lr * 520 + ((kk + lk) ^ sw0)];
      bf16x8 a1e = *(const bf16x8*)&t_flat[(size_t)(16 + lr) * 520 + ((kk + lk) ^ sw0)];
      bf16x8 a0o = *(const bf16x8*)&t_flat[(size_t)lr * 520 + ((kk + 32 + lk) ^ sw0)];
      bf16x8 a1o = *(const bf16x8*)&t_flat[(size_t)(16 + lr) * 520 + ((kk + 32 + lk) ^ sw0)];
      o[0][0] = __builtin_amdgcn_mfma_f32_16x16x32_bf16(a0e, w2f[kb],     o[0][0], 0, 0, 0);
      o[1][0] = __builtin_amdgcn_mfma_f32_16x16x32_bf16(a1e, w2f[kb],     o[1][0], 0, 0, 0);
      o[0][1] = __builtin_amdgcn_mfma_f32_16x16x32_bf16(a0o, w2f[kb + 1], o[0][1], 0, 0, 0);
      o[1][1] = __builtin_amdgcn_mfma_f32_16x16x32_bf16(a1o, w2f[kb + 1], o[1][1], 0, 0, 0);
    }
    const float* b2v = args.b2[side];
    float* outp = args.out[side];
    int col = w * 16 + lr;
    float b2c = b2v[col];
    #pragma unroll
    for (int i = 0; i < 2; ++i){
      #pragma unroll
      for (int e = 0; e < 4; ++e){
        int row = i * 16 + lg4 * 4 + e;
        float val = o[i][0][e] + o[i][1][e] + b2c + su.b.hu[(size_t)row * 132 + col];
        outp[(size_t)(rowbase + row) * 128 + col] = val;
      }
    }
  }
}

// ================= host =================
extern "C" void kernel_launch(void* const* d_in, const int* in_sizes, int n_in,
                              void* d_out, int out_size, void* d_ws, size_t ws_size,
                              hipStream_t stream) {
  (void)in_sizes; (void)n_in; (void)out_size; (void)ws_size;
  const float* h_p  = (const float*)d_in[0];
  const float* h_l  = (const float*)d_in[1];
  const float* Wq_l = (const float*)d_in[4];
  const float* Wk_p = (const float*)d_in[5];
  const float* Wv_p = (const float*)d_in[6];
  const float* Wg_l = (const float*)d_in[7];
  const float* bg_l = (const float*)d_in[8];
  const float* Wu_l = (const float*)d_in[9];
  const float* bu_l = (const float*)d_in[10];
  const float* Wq_p = (const float*)d_in[11];
  const float* Wk_l = (const float*)d_in[12];
  const float* Wv_l = (const float*)d_in[13];
  const float* Wg_p = (const float*)d_in[14];
  const float* bg_p = (const float*)d_in[15];
  const float* Wu_p = (const float*)d_in[16];
  const float* bu_p = (const float*)d_in[17];
  const float* ln_p_g = (const float*)d_in[18];
  const float* ln_p_b = (const float*)d_in[19];
  const float* ln_l_g = (const float*)d_in[20];
  const float* ln_l_b = (const float*)d_in[21];
  const float* W1_p = (const float*)d_in[22];
  const float* b1_p = (const float*)d_in[23];
  const float* W2_p = (const float*)d_in[24];
  const float* b2_p = (const float*)d_in[25];
  const float* W1_l = (const float*)d_in[26];
  const float* b1_l = (const float*)d_in[27];
  const float* W2_l = (const float*)d_in[28];
  const float* b2_l = (const float*)d_in[29];
  float* out = (float*)d_out;

  char* ws = (char*)d_ws;
  size_t off = 0;
  auto alloc = [&](size_t bytes) -> void* {
    void* p = ws + off; off += (bytes + 255) & ~(size_t)255; return p;
  };
  u16* WgT_p_T = (u16*)alloc((size_t)128 * 128 * 2);
  u16* WgB_p_T = (u16*)alloc((size_t)128 * 128 * 2);
  u16* Wu_p_T  = (u16*)alloc((size_t)128 * 128 * 2);
  u16* WgT_l_T = (u16*)alloc((size_t)128 * 128 * 2);
  u16* WgB_l_T = (u16*)alloc((size_t)128 * 128 * 2);
  u16* Wu_l_T  = (u16*)alloc((size_t)128 * 128 * 2);
  u16* W1_p_T  = (u16*)alloc((size_t)512 * 128 * 2);
  u16* W1_l_T  = (u16*)alloc((size_t)512 * 128 * 2);
  u16* W2_p_T  = (u16*)alloc((size_t)128 * 512 * 2);
  u16* W2_l_T  = (u16*)alloc((size_t)128 * 512 * 2);
  u16* qkv_p   = (u16*)alloc((size_t)NPROT * 384 * 2);
  u16* qkv_l   = (u16*)alloc((size_t)NLIG  * 384 * 2);

  // ---- K1: qkv + fragment-linear weight prep ----
  {
    L1Args a;
    a.qjobs[0] = { h_p, {Wq_p, Wk_p, Wv_p}, qkv_p, NPROT, 0 };
    a.qjobs[1] = { h_l, {Wq_l, Wk_l, Wv_l}, qkv_l, NLIG, (NPROT / 64) * 6 };
    a.nQkv = (NPROT / 64) * 6 + (NLIG / 64) * 6;   // 960
    int pbs = 0;
    int pi = 0;
    auto addT = [&](const float* s, u16* d, int K, int M){
      a.pjobs[pi].src = s; a.pjobs[pi].dst = d; a.pjobs[pi].M = M; a.pjobs[pi].K = K;
      a.pjobs[pi].tilesX = M / 32; a.pjobs[pi].blockStart = pbs;
      pbs += (K / 32) * (M / 32); ++pi;
    };
    addT(Wg_l,             WgT_l_T, 128, 128);
    addT(Wg_l + 128 * 128, WgB_l_T, 128, 128);
    addT(Wu_l,             Wu_l_T,  128, 128);
    addT(Wg_p,             WgT_p_T, 128, 128);
    addT(Wg_p + 128 * 128, WgB_p_T, 128, 128);
    addT(Wu_p,             Wu_p_T,  128, 128);
    addT(W1_p, W1_p_T, 128, 512);
    addT(W2_p, W2_p_T, 512, 128);
    addT(W1_l, W1_l_T, 128, 512);
    addT(W2_l, W2_l_T, 512, 128);
    a.nprep = pi;
    l1_kernel<<<dim3(a.nQkv + pbs), dim3(256), 0, stream>>>(a);
  }

  // ---- K2: fused per-stripe attention + tail ----
  {
    K2Args k;
    k.qkv_p = qkv_p; k.qkv_l = qkv_l;
    k.h_f[0] = h_p; k.h_f[1] = h_l;
    k.WgT[0] = WgT_p_T; k.WgT[1] = WgT_l_T;
    k.WgB[0] = WgB_p_T; k.WgB[1] = WgB_l_T;
    k.WuT[0] = Wu_p_T;  k.WuT[1] = Wu_l_T;
    k.bg[0] = bg_p; k.bg[1] = bg_l;
    k.bu[0] = bu_p; k.bu[1] = bu_l;
    k.lng[0] = ln_p_g; k.lng[1] = ln_l_g;
    k.lnb[0] = ln_p_b; k.lnb[1] = ln_l_b;
    k.W1T[0] = W1_p_T; k.W1T[1] = W1_l_T;
    k.W2T[0] = W2_p_T; k.W2T[1] = W2_l_T;
    k.b1[0] = b1_p; k.b1[1] = b1_l;
    k.b2[0] = b2_p; k.b2[1] = b2_l;
    k.out[0] = out; k.out[1] = out + (size_t)NPROT * DMODEL;
    k2_kernel<<<dim3(NLIG / 32 + NPROT / 32), dim3(512), 0, stream>>>(k);
  }
}

// Round 15
// 39.662 us; speedup vs baseline: 1.1121x; 1.1121x over previous
//
#include <hip/hip_runtime.h>
#include <hip/hip_bf16.h>

typedef __bf16 bf16x8 __attribute__((ext_vector_type(8)));
typedef __bf16 bf16x4 __attribute__((ext_vector_type(4)));
typedef float  f32x4  __attribute__((ext_vector_type(4)));
typedef unsigned short u16;

#define NPROT 8192
#define NLIG  2048
#define DMODEL 128
#define NHEAD 8
#define NBATCH 32
#define PPB 256
#define LPB 64

__device__ __forceinline__ u16 f2bf(float f){
  union { float f; unsigned int u; } v; v.f = f;
  return (u16)((v.u + 0x7FFFu + ((v.u >> 16) & 1u)) >> 16);
}

__device__ __forceinline__ bf16x8 cvt8(const float* p){
  float4 a = *(const float4*)p, b = *(const float4*)(p + 4);
  bf16x8 r;
  r[0]=(__bf16)a.x; r[1]=(__bf16)a.y; r[2]=(__bf16)a.z; r[3]=(__bf16)a.w;
  r[4]=(__bf16)b.x; r[5]=(__bf16)b.y; r[6]=(__bf16)b.z; r[7]=(__bf16)b.w;
  return r;
}

// ================= K1: qkv GEMM (LDS-staged A/W/C) + fragment-linear weight prep =================
// qkv output layout: head-major [matrix(q,k,v)][head][row][16] bf16 -> all K2 loads coalesced.
struct QkvJob { const float* A; const float* Wsrc[3]; u16* outB; int N; int blockStart; };
struct TJob { const float* src; u16* dst; int M, K, tilesX, blockStart; };
struct L1Args {
  QkvJob qjobs[2];
  int nQkv;
  int nprep;
  TJob pjobs[10];
};

__global__ __launch_bounds__(256) void l1_kernel(L1Args a){
  __shared__ u16 Wl[64][136];
  __shared__ u16 Al[64][136];
  __shared__ float tile[32][33];
  int bid = (int)blockIdx.x;
  int tid = (int)threadIdx.x;
  if (bid < a.nQkv){
    int j = (bid >= a.qjobs[1].blockStart) ? 1 : 0;
    const QkvJob jb = a.qjobs[j];
    int t = bid - jb.blockStart;
    int tn = t / 6, tm = t - tn * 6;
    // ---- stage W[128][64-col tile] -> Wl[col][k] bf16 ----
    {
      int midx = tm >> 1;
      int cb64 = (tm & 1) * 64;
      const float* Ws = jb.Wsrc[midx];
      int kr = tid >> 2;
      int cb = (tid & 3) * 16;
      #pragma unroll
      for (int p = 0; p < 2; ++p){
        int k = p * 64 + kr;
        const float* srcp = Ws + (size_t)k * 128 + cb64 + cb;
        float4 v0 = *(const float4*)srcp,     v1 = *(const float4*)(srcp + 4);
        float4 v2 = *(const float4*)(srcp+8), v3 = *(const float4*)(srcp + 12);
        float tmp[16] = {v0.x,v0.y,v0.z,v0.w, v1.x,v1.y,v1.z,v1.w,
                         v2.x,v2.y,v2.z,v2.w, v3.x,v3.y,v3.z,v3.w};
        #pragma unroll
        for (int i = 0; i < 16; ++i) Wl[cb + i][k] = f2bf(tmp[i]);
      }
    }
    // ---- stage A[64 rows][128] f32 -> Al bf16, coalesced ----
    {
      const float* Asrc = jb.A + (size_t)(tn * 64) * 128;
      #pragma unroll
      for (int p = 0; p < 8; ++p){
        int idx = p * 256 + tid;
        int r = idx >> 5, c4 = (idx & 31) * 4;
        float4 v = *(const float4*)(Asrc + (size_t)r * 128 + c4);
        Al[r][c4+0] = f2bf(v.x); Al[r][c4+1] = f2bf(v.y);
        Al[r][c4+2] = f2bf(v.z); Al[r][c4+3] = f2bf(v.w);
      }
    }
    __syncthreads();
    int w = tid >> 6, l = tid & 63;
    int rloc = (w >> 1) * 32;
    int cloc = (w & 1) * 32;
    int lr = l & 15, lk = (l >> 4) * 8;
    f32x4 a00 = {0.f,0.f,0.f,0.f}, a01 = a00, a10 = a00, a11 = a00;
    #pragma unroll
    for (int kk = 0; kk < 128; kk += 32){
      bf16x8 a0 = *(const bf16x8*)&Al[rloc + lr][kk + lk];
      bf16x8 a1 = *(const bf16x8*)&Al[rloc + 16 + lr][kk + lk];
      bf16x8 b0 = *(const bf16x8*)&Wl[cloc + lr][kk + lk];
      bf16x8 b1 = *(const bf16x8*)&Wl[cloc + 16 + lr][kk + lk];
      a00 = __builtin_amdgcn_mfma_f32_16x16x32_bf16(a0, b0, a00, 0, 0, 0);
      a01 = __builtin_amdgcn_mfma_f32_16x16x32_bf16(a0, b1, a01, 0, 0, 0);
      a10 = __builtin_amdgcn_mfma_f32_16x16x32_bf16(a1, b0, a10, 0, 0, 0);
      a11 = __builtin_amdgcn_mfma_f32_16x16x32_bf16(a1, b1, a11, 0, 0, 0);
    }
    __syncthreads();   // Al reads done -> reuse Al as C staging
    {
      f32x4 av[2][2] = {{a00, a01}, {a10, a11}};
      int lg4 = l >> 4;
      #pragma unroll
      for (int i = 0; i < 2; ++i)
        #pragma unroll
        for (int jj = 0; jj < 2; ++jj)
          #pragma unroll
          for (int e = 0; e < 4; ++e)
            Al[rloc + i * 16 + lg4 * 4 + e][cloc + jj * 16 + lr] = f2bf(av[i][jj][e]);
    }
    __syncthreads();
    // coalesced head-major store: [m][h][row][16]
    {
      int row = tid >> 2;          // 0..63
      int hseg = tid & 3;          // 0..3
      int m = tm >> 1;
      int h = (tm & 1) * 4 + hseg;
      const u16* srcl = &Al[row][hseg * 16];
      u16* dst = jb.outB + ((size_t)m * NHEAD + h) * (size_t)jb.N * 16
                         + (size_t)(tn * 64 + row) * 16;
      *(bf16x8*)dst = *(const bf16x8*)srcl;
      *(bf16x8*)(dst + 8) = *(const bf16x8*)(srcl + 8);
    }
  } else {
    int pb = bid - a.nQkv;
    int j = 0;
    while (j + 1 < a.nprep && pb >= a.pjobs[j + 1].blockStart) ++j;
    const TJob jb = a.pjobs[j];
    int t = pb - jb.blockStart;
    int tm = t % jb.tilesX, tk = t / jb.tilesX;
    int c = tid & 31, r0 = tid >> 5;
    #pragma unroll
    for (int p = 0; p < 4; ++p)
      tile[r0 + p * 8][c] = jb.src[(size_t)(tk * 32 + r0 + p * 8) * jb.M + tm * 32 + c];
    __syncthreads();
    // fragment-linear writer: chunk (cb = tm*2 + c2, kb = tk)
    {
      int c2 = tid >> 7;
      int lch = (tid >> 1) & 63;
      int eh = (tid & 1) * 4;
      int kl = (lch >> 4) * 8 + eh;
      int ml = c2 * 16 + (lch & 15);
      ushort4 o;
      o.x = f2bf(tile[kl + 0][ml]);
      o.y = f2bf(tile[kl + 1][ml]);
      o.z = f2bf(tile[kl + 2][ml]);
      o.w = f2bf(tile[kl + 3][ml]);
      size_t off = ((size_t)(tm * 2 + c2) * (jb.K >> 5) + tk) * 512 + lch * 8 + eh;
      *(ushort4*)&jb.dst[off] = o;
    }
  }
}

// ================= K2: fused attn + tail; 32-row stripes, 8 waves, frag-linear weights =================
struct K2Args {
  const u16 *qkv_p, *qkv_l;
  const float *h_f[2];
  const u16 *WgT[2], *WgB[2], *WuT[2];
  const float *bg[2], *bu[2], *lng[2], *lnb[2];
  const u16 *W1T[2], *W2T[2];
  const float *b1[2], *b2[2];
  float* out[2];
};

struct K2B {
  float hu[32 * 132];
  union { float hstg[32 * 132]; u16 t[32 * 520]; } x;
};

__global__ __launch_bounds__(512) void k2_kernel(K2Args args){
  __shared__ __align__(16) union {
    struct { u16 vT[8 * 1152]; u16 P[8 * 2304]; } a;   // per-wave V^T[16][72], P[32][72]
    K2B b;                                              // tail temporaries
  } su;
  __shared__ __align__(16) u16 s_ctx[32 * 128];        // swizzled ctx, reused as xln

  int bid = (int)blockIdx.x;
  int tid = (int)threadIdx.x;
  int w = tid >> 6, l = tid & 63, lr = l & 15, lg4 = l >> 4;
  int lk = lg4 * 8;

  int side, rowbase, batch, NC;
  if (bid < NLIG / 32){ side = 1; rowbase = bid * 32; batch = rowbase >> 6; NC = 4; }
  else { side = 0; rowbase = (bid - NLIG / 32) * 32; batch = rowbase >> 8; NC = 1; }

  int NRs = side == 0 ? NPROT : NLIG;
  int NRo = side == 0 ? NLIG : NPROT;
  int orowoff = side == 0 ? batch * LPB : batch * PPB;
  const u16* qbase = (side == 0 ? args.qkv_p : args.qkv_l);
  const u16* obase = (side == 0 ? args.qkv_l : args.qkv_p);
  const u16* kbase = obase + (size_t)NHEAD * NRo * 16;
  const u16* vbase = obase + (size_t)2 * NHEAD * NRo * 16;

  bf16x8 zero8;
  #pragma unroll
  for (int i = 0; i < 8; ++i) zero8[i] = (__bf16)0.f;

  u16* vTw = su.a.vT + w * 1152;
  u16* Pw  = su.a.P  + w * 2304;
  int h = w;   // one head per wave, all 32 q-rows

  // ---- attention: online softmax over 64-key chunks, 2 q-fragments ----
  {
    bf16x8 qf[2];
    #pragma unroll
    for (int qt = 0; qt < 2; ++qt)
      qf[qt] = (l < 32)
        ? *(const bf16x8*)(qbase + ((size_t)h * NRs + rowbase + qt * 16 + lr) * 16 + lk)
        : zero8;
    f32x4 Ot[2]; float mv[2], ls[2];
    #pragma unroll
    for (int qt = 0; qt < 2; ++qt){ Ot[qt] = (f32x4){0.f,0.f,0.f,0.f}; mv[qt] = -1e30f; ls[qt] = 0.f; }
    for (int c = 0; c < NC; ++c){
      { // stage V^T chunk: key = c*64 + l; contiguous 32 B/lane
        const u16* vs = vbase + ((size_t)h * NRo + orowoff + c * 64 + l) * 16;
        bf16x8 v0 = *(const bf16x8*)vs;
        bf16x8 v1 = *(const bf16x8*)(vs + 8);
        #pragma unroll
        for (int i = 0; i < 8; ++i){
          vTw[i * 72 + l]       = ((const u16*)&v0)[i];
          vTw[(i + 8) * 72 + l] = ((const u16*)&v1)[i];
        }
      }
      bf16x8 kf[4];
      #pragma unroll
      for (int kt = 0; kt < 4; ++kt)
        kf[kt] = (l < 32)
          ? *(const bf16x8*)(kbase + ((size_t)h * NRo + orowoff + c * 64 + kt * 16 + lr) * 16 + lk)
          : zero8;
      f32x4 sa[4][2];
      #pragma unroll
      for (int kt = 0; kt < 4; ++kt)
        #pragma unroll
        for (int qt = 0; qt < 2; ++qt)
          sa[kt][qt] = __builtin_amdgcn_mfma_f32_16x16x32_bf16(kf[kt], qf[qt], (f32x4){0.f,0.f,0.f,0.f}, 0, 0, 0);
      #pragma unroll
      for (int qt = 0; qt < 2; ++qt){
        float cm = -1e30f;
        #pragma unroll
        for (int kt = 0; kt < 4; ++kt)
          #pragma unroll
          for (int e = 0; e < 4; ++e) cm = fmaxf(cm, sa[kt][qt][e]);
        cm = fmaxf(cm, __shfl_xor(cm, 16)); cm = fmaxf(cm, __shfl_xor(cm, 32));
        float mn = fmaxf(mv[qt], cm);
        float resc = __expf((mv[qt] - mn) * 0.25f);
        mv[qt] = mn;
        float cs = 0.f;
        #pragma unroll
        for (int kt = 0; kt < 4; ++kt){
          bf16x4 pk;
          #pragma unroll
          for (int e = 0; e < 4; ++e){
            float p = __expf((sa[kt][qt][e] - mn) * 0.25f);
            cs += p; pk[e] = (__bf16)p;
          }
          *(bf16x4*)&Pw[(size_t)(qt * 16 + lr) * 72 + kt * 16 + lg4 * 4] = pk;
        }
        cs += __shfl_xor(cs, 16); cs += __shfl_xor(cs, 32);
        ls[qt] = ls[qt] * resc + cs;
        Ot[qt] = Ot[qt] * resc;
      }
      #pragma unroll
      for (int ks = 0; ks < 2; ++ks){
        bf16x8 va = *(const bf16x8*)&vTw[(size_t)lr * 72 + ks * 32 + lg4 * 8];
        #pragma unroll
        for (int qt = 0; qt < 2; ++qt){
          bf16x8 pb = *(const bf16x8*)&Pw[(size_t)(qt * 16 + lr) * 72 + ks * 32 + lg4 * 8];
          Ot[qt] = __builtin_amdgcn_mfma_f32_16x16x32_bf16(va, pb, Ot[qt], 0, 0, 0);
        }
      }
    }
    #pragma unroll
    for (int qt = 0; qt < 2; ++qt){
      float inv = 1.f / ls[qt];
      int q = qt * 16 + lr;
      int dbase = h * 16 + lg4 * 4;
      bf16x4 ov;
      #pragma unroll
      for (int e = 0; e < 4; ++e) ov[e] = (__bf16)(Ot[qt][e] * inv);
      *(bf16x4*)&s_ctx[(size_t)q * 128 + (dbase ^ ((q & 7) << 3))] = ov;
    }
  }
  __syncthreads();

  // ---- stage h[32][128] f32 coalesced into LDS (dead attn region) ----
  {
    const float* hsrc = args.h_f[side] + (size_t)rowbase * 128;
    #pragma unroll
    for (int p = 0; p < 2; ++p){
      int idx = p * 512 + tid;
      int r = idx >> 5, c4 = (idx & 31) * 4;
      *(float4*)&su.b.x.hstg[(size_t)r * 132 + c4] = *(const float4*)(hsrc + (size_t)r * 128 + c4);
    }
  }
  __syncthreads();

  // ---- stage 1: glin (K=256: h|ctx) + u (K=128: ctx); frag-linear weight streams ----
  {
    bf16x8 wg[4], wc[4], wu[4];
    {
      const u16* bgp = args.WgT[side] + (size_t)(w * 4) * 512 + l * 8;
      const u16* bcp = args.WgB[side] + (size_t)(w * 4) * 512 + l * 8;
      const u16* bup = args.WuT[side] + (size_t)(w * 4) * 512 + l * 8;
      #pragma unroll
      for (int kb = 0; kb < 4; ++kb) wg[kb] = *(const bf16x8*)(bgp + kb * 512);
      #pragma unroll
      for (int kb = 0; kb < 4; ++kb) wc[kb] = *(const bf16x8*)(bcp + kb * 512);
      #pragma unroll
      for (int kb = 0; kb < 4; ++kb) wu[kb] = *(const bf16x8*)(bup + kb * 512);
    }
    f32x4 g0 = {0.f,0.f,0.f,0.f}, g1 = g0, u0 = g0, u1 = g0;
    const float* hst = su.b.x.hstg;
    int swa = (lr & 7) << 3;
    #pragma unroll
    for (int kb = 0; kb < 4; ++kb){
      int kk = kb * 32;
      bf16x8 ah0 = cvt8(hst + (size_t)lr * 132 + kk);
      bf16x8 ah1 = cvt8(hst + (size_t)(16 + lr) * 132 + kk);
      bf16x8 ac0 = *(const bf16x8*)&s_ctx[(size_t)lr * 128 + ((kk + lk) ^ swa)];
      bf16x8 ac1 = *(const bf16x8*)&s_ctx[(size_t)(16 + lr) * 128 + ((kk + lk) ^ swa)];
      g0 = __builtin_amdgcn_mfma_f32_16x16x32_bf16(ah0, wg[kb], g0, 0, 0, 0);
      g1 = __builtin_amdgcn_mfma_f32_16x16x32_bf16(ah1, wg[kb], g1, 0, 0, 0);
      g0 = __builtin_amdgcn_mfma_f32_16x16x32_bf16(ac0, wc[kb], g0, 0, 0, 0);
      g1 = __builtin_amdgcn_mfma_f32_16x16x32_bf16(ac1, wc[kb], g1, 0, 0, 0);
      u0 = __builtin_amdgcn_mfma_f32_16x16x32_bf16(ac0, wu[kb], u0, 0, 0, 0);
      u1 = __builtin_amdgcn_mfma_f32_16x16x32_bf16(ac1, wu[kb], u1, 0, 0, 0);
    }
    int col = w * 16 + lr;
    float bgc = args.bg[side][col];
    float buc = args.bu[side][col];
    #pragma unroll
    for (int i = 0; i < 2; ++i){
      f32x4 gv4 = i ? g1 : g0;
      f32x4 uv4 = i ? u1 : u0;
      #pragma unroll
      for (int e = 0; e < 4; ++e){
        int row = i * 16 + lg4 * 4 + e;
        float gv = gv4[e] + bgc;
        float uv = uv4[e] + buc;
        float hv = hst[(size_t)row * 132 + col];
        float sg = 1.f / (1.f + __expf(-gv));
        su.b.hu[(size_t)row * 132 + col] = hv + sg * uv;
      }
    }
  }
  __syncthreads();

  // ---- stage 2: LayerNorm -> xln (overwrites s_ctx, swizzled); 16 thr/row ----
  {
    int r = tid >> 4;
    int sub = tid & 15;
    float x[8];
    #pragma unroll
    for (int i = 0; i < 2; ++i){
      float4 v4 = *(const float4*)&su.b.hu[(size_t)r * 132 + sub * 8 + i * 4];
      x[i*4+0] = v4.x; x[i*4+1] = v4.y; x[i*4+2] = v4.z; x[i*4+3] = v4.w;
    }
    float s = 0.f;
    #pragma unroll
    for (int i = 0; i < 8; ++i) s += x[i];
    s += __shfl_xor(s, 1); s += __shfl_xor(s, 2); s += __shfl_xor(s, 4); s += __shfl_xor(s, 8);
    float mu = s * (1.f / 128.f);
    float vv = 0.f;
    #pragma unroll
    for (int i = 0; i < 8; ++i){ float d = x[i] - mu; vv += d * d; }
    vv += __shfl_xor(vv, 1); vv += __shfl_xor(vv, 2); vv += __shfl_xor(vv, 4); vv += __shfl_xor(vv, 8);
    float rs = rsqrtf(vv * (1.f / 128.f) + 1e-5f);
    const float* lg2 = args.lng[side];
    const float* lb = args.lnb[side];
    int sw = (r & 7) << 3;
    #pragma unroll
    for (int i = 0; i < 8; ++i){
      int col = sub * 8 + i;
      s_ctx[(size_t)r * 128 + (col ^ sw)] = f2bf((x[i] - mu) * rs * lg2[col] + lb[col]);
    }
  }
  __syncthreads();

  // ---- stage 3: FFN1 t = relu(xln @ W1 + b1); frag-linear W1 stream (16 chunks/wave) ----
  {
    bf16x8 w1f[16];
    {
      const u16* b1p = args.W1T[side] + (size_t)(w * 16) * 512 + l * 8;
      #pragma unroll
      for (int q = 0; q < 16; ++q) w1f[q] = *(const bf16x8*)(b1p + q * 512);
    }
    f32x4 acc[2][4];
    #pragma unroll
    for (int i = 0; i < 2; ++i)
      #pragma unroll
      for (int jj = 0; jj < 4; ++jj) acc[i][jj] = (f32x4){0.f,0.f,0.f,0.f};
    int sw0 = (lr & 7) << 3;
    #pragma unroll
    for (int kb = 0; kb < 4; ++kb){
      int kk = kb * 32;
      bf16x8 a0 = *(const bf16x8*)&s_ctx[(size_t)lr * 128 + ((kk + lk) ^ sw0)];
      bf16x8 a1 = *(const bf16x8*)&s_ctx[(size_t)(16 + lr) * 128 + ((kk + lk) ^ sw0)];
      #pragma unroll
      for (int jj = 0; jj < 4; ++jj){
        acc[0][jj] = __builtin_amdgcn_mfma_f32_16x16x32_bf16(a0, w1f[jj * 4 + kb], acc[0][jj], 0, 0, 0);
        acc[1][jj] = __builtin_amdgcn_mfma_f32_16x16x32_bf16(a1, w1f[jj * 4 + kb], acc[1][jj], 0, 0, 0);
      }
    }
    const float* b1v = args.b1[side];
    u16* t_flat = su.b.x.t;
    #pragma unroll
    for (int i = 0; i < 2; ++i)
      #pragma unroll
      for (int jj = 0; jj < 4; ++jj)
        #pragma unroll
        for (int e = 0; e < 4; ++e){
          int row = i * 16 + lg4 * 4 + e;
          int col = w * 64 + jj * 16 + lr;
          float v = fmaxf(acc[i][jj][e] + b1v[col], 0.f);
          t_flat[(size_t)row * 520 + (col ^ ((row & 7) << 3))] = f2bf(v);
        }
  }
  __syncthreads();

  // ---- stage 4: FFN2 out = t @ W2 + b2 + hu; frag-linear W2 stream, dual-parity acc ----
  {
    bf16x8 w2f[16];
    {
      const u16* b2p = args.W2T[side] + (size_t)(w * 16) * 512 + l * 8;
      #pragma unroll
      for (int q = 0; q < 16; ++q) w2f[q] = *(const bf16x8*)(b2p + q * 512);
    }
    f32x4 o[2][2];
    #pragma unroll
    for (int i = 0; i < 2; ++i)
      #pragma unroll
      for (int p = 0; p < 2; ++p) o[i][p] = (f32x4){0.f,0.f,0.f,0.f};
    const u16* t_flat = su.b.x.t;
    int sw0 = (lr & 7) << 3;
    #pragma unroll
    for (int kb = 0; kb < 16; kb += 2){
      int kk = kb * 32;
      bf16x8 a0e = *(const bf16x8*)&t_flat[(size_t)lr * 520 + ((kk + lk) ^ sw0)];
      bf16x8 a1e = *(const bf16x8*)&t_flat[(size_t)(16 + lr) * 520 + ((kk + lk) ^ sw0)];
      bf16x8 a0o = *(const bf16x8*)&t_flat[(size_t)lr * 520 + ((kk + 32 + lk) ^ sw0)];
      bf16x8 a1o = *(const bf16x8*)&t_flat[(size_t)(16 + lr) * 520 + ((kk + 32 + lk) ^ sw0)];
      o[0][0] = __builtin_amdgcn_mfma_f32_16x16x32_bf16(a0e, w2f[kb],     o[0][0], 0, 0, 0);
      o[1][0] = __builtin_amdgcn_mfma_f32_16x16x32_bf16(a1e, w2f[kb],     o[1][0], 0, 0, 0);
      o[0][1] = __builtin_amdgcn_mfma_f32_16x16x32_bf16(a0o, w2f[kb + 1], o[0][1], 0, 0, 0);
      o[1][1] = __builtin_amdgcn_mfma_f32_16x16x32_bf16(a1o, w2f[kb + 1], o[1][1], 0, 0, 0);
    }
    const float* b2v = args.b2[side];
    float* outp = args.out[side];
    int col = w * 16 + lr;
    float b2c = b2v[col];
    #pragma unroll
    for (int i = 0; i < 2; ++i){
      #pragma unroll
      for (int e = 0; e < 4; ++e){
        int row = i * 16 + lg4 * 4 + e;
        float val = o[i][0][e] + o[i][1][e] + b2c + su.b.hu[(size_t)row * 132 + col];
        outp[(size_t)(rowbase + row) * 128 + col] = val;
      }
    }
  }
}

// ================= host =================
extern "C" void kernel_launch(void* const* d_in, const int* in_sizes, int n_in,
                              void* d_out, int out_size, void* d_ws, size_t ws_size,
                              hipStream_t stream) {
  (void)in_sizes; (void)n_in; (void)out_size; (void)ws_size;
  const float* h_p  = (const float*)d_in[0];
  const float* h_l  = (const float*)d_in[1];
  const float* Wq_l = (const float*)d_in[4];
  const float* Wk_p = (const float*)d_in[5];
  const float* Wv_p = (const float*)d_in[6];
  const float* Wg_l = (const float*)d_in[7];
  const float* bg_l = (const float*)d_in[8];
  const float* Wu_l = (const float*)d_in[9];
  const float* bu_l = (const float*)d_in[10];
  const float* Wq_p = (const float*)d_in[11];
  const float* Wk_l = (const float*)d_in[12];
  const float* Wv_l = (const float*)d_in[13];
  const float* Wg_p = (const float*)d_in[14];
  const float* bg_p = (const float*)d_in[15];
  const float* Wu_p = (const float*)d_in[16];
  const float* bu_p = (const float*)d_in[17];
  const float* ln_p_g = (const float*)d_in[18];
  const float* ln_p_b = (const float*)d_in[19];
  const float* ln_l_g = (const float*)d_in[20];
  const float* ln_l_b = (const float*)d_in[21];
  const float* W1_p = (const float*)d_in[22];
  const float* b1_p = (const float*)d_in[23];
  const float* W2_p = (const float*)d_in[24];
  const float* b2_p = (const float*)d_in[25];
  const float* W1_l = (const float*)d_in[26];
  const float* b1_l = (const float*)d_in[27];
  const float* W2_l = (const float*)d_in[28];
  const float* b2_l = (const float*)d_in[29];
  float* out = (float*)d_out;

  char* ws = (char*)d_ws;
  size_t off = 0;
  auto alloc = [&](size_t bytes) -> void* {
    void* p = ws + off; off += (bytes + 255) & ~(size_t)255; return p;
  };
  u16* WgT_p_T = (u16*)alloc((size_t)128 * 128 * 2);
  u16* WgB_p_T = (u16*)alloc((size_t)128 * 128 * 2);
  u16* Wu_p_T  = (u16*)alloc((size_t)128 * 128 * 2);
  u16* WgT_l_T = (u16*)alloc((size_t)128 * 128 * 2);
  u16* WgB_l_T = (u16*)alloc((size_t)128 * 128 * 2);
  u16* Wu_l_T  = (u16*)alloc((size_t)128 * 128 * 2);
  u16* W1_p_T  = (u16*)alloc((size_t)512 * 128 * 2);
  u16* W1_l_T  = (u16*)alloc((size_t)512 * 128 * 2);
  u16* W2_p_T  = (u16*)alloc((size_t)128 * 512 * 2);
  u16* W2_l_T  = (u16*)alloc((size_t)128 * 512 * 2);
  u16* qkv_p   = (u16*)alloc((size_t)NPROT * 384 * 2);
  u16* qkv_l   = (u16*)alloc((size_t)NLIG  * 384 * 2);

  // ---- K1: qkv + fragment-linear weight prep ----
  {
    L1Args a;
    a.qjobs[0] = { h_p, {Wq_p, Wk_p, Wv_p}, qkv_p, NPROT, 0 };
    a.qjobs[1] = { h_l, {Wq_l, Wk_l, Wv_l}, qkv_l, NLIG, (NPROT / 64) * 6 };
    a.nQkv = (NPROT / 64) * 6 + (NLIG / 64) * 6;   // 960
    int pbs = 0;
    int pi = 0;
    auto addT = [&](const float* s, u16* d, int K, int M){
      a.pjobs[pi].src = s; a.pjobs[pi].dst = d; a.pjobs[pi].M = M; a.pjobs[pi].K = K;
      a.pjobs[pi].tilesX = M / 32; a.pjobs[pi].blockStart = pbs;
      pbs += (K / 32) * (M / 32); ++pi;
    };
    addT(Wg_l,             WgT_l_T, 128, 128);
    addT(Wg_l + 128 * 128, WgB_l_T, 128, 128);
    addT(Wu_l,             Wu_l_T,  128, 128);
    addT(Wg_p,             WgT_p_T, 128, 128);
    addT(Wg_p + 128 * 128, WgB_p_T, 128, 128);
    addT(Wu_p,             Wu_p_T,  128, 128);
    addT(W1_p, W1_p_T, 128, 512);
    addT(W2_p, W2_p_T, 512, 128);
    addT(W1_l, W1_l_T, 128, 512);
    addT(W2_l, W2_l_T, 512, 128);
    a.nprep = pi;
    l1_kernel<<<dim3(a.nQkv + pbs), dim3(256), 0, stream>>>(a);
  }

  // ---- K2: fused per-stripe attention + tail ----
  {
    K2Args k;
    k.qkv_p = qkv_p; k.qkv_l = qkv_l;
    k.h_f[0] = h_p; k.h_f[1] = h_l;
    k.WgT[0] = WgT_p_T; k.WgT[1] = WgT_l_T;
    k.WgB[0] = WgB_p_T; k.WgB[1] = WgB_l_T;
    k.WuT[0] = Wu_p_T;  k.WuT[1] = Wu_l_T;
    k.bg[0] = bg_p; k.bg[1] = bg_l;
    k.bu[0] = bu_p; k.bu[1] = bu_l;
    k.lng[0] = ln_p_g; k.lng[1] = ln_l_g;
    k.lnb[0] = ln_p_b; k.lnb[1] = ln_l_b;
    k.W1T[0] = W1_p_T; k.W1T[1] = W1_l_T;
    k.W2T[0] = W2_p_T; k.W2T[1] = W2_l_T;
    k.b1[0] = b1_p; k.b1[1] = b1_l;
    k.b2[0] = b2_p; k.b2[1] = b2_l;
    k.out[0] = out; k.out[1] = out + (size_t)NPROT * DMODEL;
    k2_kernel<<<dim3(NLIG / 32 + NPROT / 32), dim3(512), 0, stream>>>(k);
  }
}